// Round 7
// baseline (176.793 us; speedup 1.0000x reference)
//
#include <hip/hip_runtime.h>

#define NJ 24
#define NF 7
#define FS 6
#define THREADS 256
#define CUNITS 12   // float4 per thread per chunk (4 joint-pairs = 192 B)
#define PAD 13      // LDS stride in float4 units

// parent of each joint; parents[i] < i, so sequential order is topological
__device__ constexpr int kParents[NJ] = {-1, 0, 0, 0, 1, 2, 3, 4, 5, 6, 7, 8,
                                          9, 9, 9, 12, 13, 14, 16, 17, 18, 19, 20, 21};

// Compute joint i for one sample. XC = current chunk's 8 x-values.
// DOSTAGE=1: stage completed joint-pairs into LDS (sample-A path).
// DOSTAGE=0: keep feats in registers (sample-B path, staged later in a burst).
#define JOINT(i, XC, FEATS, DOSTAGE)                                          \
    {                                                                         \
        const int p_ = kParents[i];                                           \
        float inp_[NF];                                                       \
        inp_[0] = XC[(i) & 7];                                                \
        _Pragma("unroll")                                                     \
        for (int j = 0; j < FS; ++j)                                          \
            inp_[1 + j] = (p_ < 0) ? 0.0f : FEATS[(p_ < 0) ? 0 : p_][j];      \
        float h_[NF];                                                         \
        _Pragma("unroll")                                                     \
        for (int j = 0; j < NF; ++j) h_[j] = b1[(i) * NF + j];                \
        _Pragma("unroll")                                                     \
        for (int k = 0; k < NF; ++k) {                                        \
            const float a_ = inp_[k];                                         \
            _Pragma("unroll")                                                 \
            for (int j = 0; j < NF; ++j)                                      \
                h_[j] = fmaf(a_, W1[(i) * NF * NF + k * NF + j], h_[j]);      \
        }                                                                     \
        _Pragma("unroll")                                                     \
        for (int j = 0; j < NF; ++j) h_[j] = fmaxf(h_[j], 0.0f);              \
        float f_[FS];                                                         \
        _Pragma("unroll")                                                     \
        for (int j = 0; j < FS; ++j) f_[j] = b2[(i) * FS + j];                \
        _Pragma("unroll")                                                     \
        for (int k = 0; k < NF; ++k) {                                        \
            const float a_ = h_[k];                                           \
            _Pragma("unroll")                                                 \
            for (int j = 0; j < FS; ++j)                                      \
                f_[j] = fmaf(a_, W2[(i) * NF * FS + k * FS + j], f_[j]);      \
        }                                                                     \
        _Pragma("unroll")                                                     \
        for (int j = 0; j < FS; ++j) {                                        \
            f_[j] = fmaxf(f_[j], 0.0f);                                       \
            FEATS[i][j] = f_[j];                                              \
        }                                                                     \
        if ((DOSTAGE) && ((i) & 1)) { /* stage pair (i-1, i): 3 x float4 */   \
            const int pp_ = ((i) >> 1) & 3;                                   \
            float4* st_ = myStage + pp_ * 3;                                  \
            st_[0] = make_float4(FEATS[(i) - 1][0], FEATS[(i) - 1][1],        \
                                 FEATS[(i) - 1][2], FEATS[(i) - 1][3]);       \
            st_[1] = make_float4(FEATS[(i) - 1][4], FEATS[(i) - 1][5],        \
                                 f_[0], f_[1]);                               \
            st_[2] = make_float4(f_[2], f_[3], f_[4], f_[5]);                 \
        }                                                                     \
    }

// Burst-stage sample B's chunk C (pairs come from registers).
#define STAGE_B(C)                                                            \
    {                                                                         \
        _Pragma("unroll")                                                     \
        for (int pp = 0; pp < 4; ++pp) {                                      \
            const int i0 = (C) * 8 + 2 * pp;                                  \
            float4* st_ = myStage + pp * 3;                                   \
            st_[0] = make_float4(feats1[i0][0], feats1[i0][1],                \
                                 feats1[i0][2], feats1[i0][3]);               \
            st_[1] = make_float4(feats1[i0][4], feats1[i0][5],                \
                                 feats1[i0 + 1][0], feats1[i0 + 1][1]);       \
            st_[2] = make_float4(feats1[i0 + 1][2], feats1[i0 + 1][3],        \
                                 feats1[i0 + 1][4], feats1[i0 + 1][5]);       \
        }                                                                     \
    }

// R3's proven burst flush: 12 x (ds_read_b128 -> global_store_dwordx4),
// each wave-store = 16 complete 64B lines; values die immediately (low VGPR).
#define FLUSH(WB, C)                                                          \
    {                                                                         \
        _Pragma("unroll")                                                     \
        for (int j = 0; j < CUNITS; ++j) {                                    \
            const int G = j * 64 + lane;                                      \
            const int s = G / CUNITS;                                         \
            const int q = G - s * CUNITS;                                     \
            float4 v = sm[wid][s * PAD + q];                                  \
            outv[(size_t)(WB) * 36 + (C) * 12 + s * 36 + q] = v;              \
        }                                                                     \
    }

// Load chunk C's 8 x-values for both samples (2 x float4 each).
#define LOADX(C)                                                              \
    {                                                                         \
        float4 a0 = xvA[2 * (C)], a1 = xvA[2 * (C) + 1];                      \
        float4 b0_ = xvB[2 * (C)], b1_ = xvB[2 * (C) + 1];                    \
        xcA[0] = a0.x; xcA[1] = a0.y; xcA[2] = a0.z; xcA[3] = a0.w;           \
        xcA[4] = a1.x; xcA[5] = a1.y; xcA[6] = a1.z; xcA[7] = a1.w;           \
        xcB[0] = b0_.x; xcB[1] = b0_.y; xcB[2] = b0_.z; xcB[3] = b0_.w;       \
        xcB[4] = b1_.x; xcB[5] = b1_.y; xcB[6] = b1_.z; xcB[7] = b1_.w;       \
    }

#define JPAIR(i) JOINT(i, xcA, feats0, 1) JOINT(i, xcB, feats1, 0)

// Requires B % 512 == 0 (bench: B = 524288).
__global__ __launch_bounds__(THREADS, 3) void se1d_kernel(
    const float* __restrict__ x,
    const float* __restrict__ W1,
    const float* __restrict__ b1,
    const float* __restrict__ W2,
    const float* __restrict__ b2,
    float* __restrict__ out, int B)
{
    // Wave-private staging: 64 lanes x 13 float4 = 13312 B/wave, 53 KB/block
    // -> 3 blocks/CU (12 waves). No barriers: wave-synchronous; per-wave DS
    // pipe is in-order, so FLUSH(A) reads issued before STAGE_B writes get
    // old data, and FLUSH(B) reads after STAGE_B writes get new data.
    __shared__ float4 sm[THREADS / 64][64 * PAD];

    const int t    = threadIdx.x;
    const int lane = t & 63;
    const int wid  = t >> 6;
    const int base = blockIdx.x * (THREADS * 2);
    const int bA   = base + t;                         // sample A
    const int bB   = base + THREADS + t;               // sample B
    const int wb0  = base + wid * 64;                  // wave A base
    const int wb1  = base + THREADS + wid * 64;        // wave B base

    float4* const myStage = &sm[wid][lane * PAD];
    float4* const outv = reinterpret_cast<float4*>(out);
    const float4* xvA = reinterpret_cast<const float4*>(x + (size_t)bA * NJ);
    const float4* xvB = reinterpret_cast<const float4*>(x + (size_t)bB * NJ);

    float xcA[8], xcB[8];          // current chunk's x only (low pressure)
    float feats0[NJ][FS], feats1[NJ][FS];  // unrolled -> registers, windowed

    // ---- chunk 0 ----
    LOADX(0);
    JPAIR(0) JPAIR(1) JPAIR(2) JPAIR(3)
    JPAIR(4) JPAIR(5) JPAIR(6) JPAIR(7)
    LOADX(1);                      // prefetch next chunk's x before flushes
    FLUSH(wb0, 0);
    STAGE_B(0);
    FLUSH(wb1, 0);
    // ---- chunk 1 ----
    JPAIR(8) JPAIR(9) JPAIR(10) JPAIR(11)
    JPAIR(12) JPAIR(13) JPAIR(14) JPAIR(15)
    LOADX(2);
    FLUSH(wb0, 1);
    STAGE_B(1);
    FLUSH(wb1, 1);
    // ---- chunk 2 ----
    JPAIR(16) JPAIR(17) JPAIR(18) JPAIR(19)
    JPAIR(20) JPAIR(21) JPAIR(22) JPAIR(23)
    FLUSH(wb0, 2);
    STAGE_B(2);
    FLUSH(wb1, 2);
    (void)B;
}

extern "C" void kernel_launch(void* const* d_in, const int* in_sizes, int n_in,
                              void* d_out, int out_size, void* d_ws, size_t ws_size,
                              hipStream_t stream) {
    const float* x  = (const float*)d_in[0];
    const float* W1 = (const float*)d_in[1];
    const float* b1 = (const float*)d_in[2];
    const float* W2 = (const float*)d_in[3];
    const float* b2 = (const float*)d_in[4];
    float* out = (float*)d_out;
    const int B = in_sizes[0] / NJ;   // 524288, multiple of 512
    const int grid = B / (THREADS * 2);
    hipLaunchKernelGGL(se1d_kernel, dim3(grid), dim3(THREADS), 0, stream,
                       x, W1, b1, W2, b2, out, B);
}

// Round 8
// 96.301 us; speedup vs baseline: 1.8358x; 1.8358x over previous
//
#include <hip/hip_runtime.h>

#define NJ 24
#define NF 7
#define FS 6
#define THREADS 256
#define CUNITS 12   // float4 per thread per chunk (4 joint-pairs = 192 B)
#define PAD 13      // LDS stride in float4 units

typedef float v4f __attribute__((ext_vector_type(4)));

// parent of each joint; parents[i] < i, so sequential order is topological
__device__ constexpr int kParents[NJ] = {-1, 0, 0, 0, 1, 2, 3, 4, 5, 6, 7, 8,
                                          9, 9, 9, 12, 13, 14, 16, 17, 18, 19, 20, 21};

// Requires B % 256 == 0 (bench: B = 524288).
__global__ __launch_bounds__(THREADS, 3) void se1d_kernel(
    const float* __restrict__ x,
    const float* __restrict__ W1,
    const float* __restrict__ b1,
    const float* __restrict__ W2,
    const float* __restrict__ b2,
    float* __restrict__ out, int B)
{
    // Wave-private staging: 64 lanes x 13 float4 = 13312 B/wave, 53 KB/block
    // -> 3 blocks/CU (12 waves). No barriers (wave-synchronous; per-wave DS
    // pipe is in-order, so flush-reads issued before the next chunk's
    // stage-writes return the old, correct data).
    __shared__ float4 sm[THREADS / 64][64 * PAD];

    const int t    = threadIdx.x;
    const int lane = t & 63;
    const int wid  = t >> 6;
    const int b    = blockIdx.x * THREADS + t;         // this thread's sample
    const int wb   = blockIdx.x * THREADS + wid * 64;  // wave's sample base

    float4* const myStage = &sm[wid][lane * PAD];
    v4f* const outv = reinterpret_cast<v4f*>(out);

    // x is a read-once stream: non-temporal loads keep it from evicting the
    // 10 KB weight set out of L2 (the R7 counters showed grid x 10KB excess
    // FETCH = weights re-missing L2 every block).
    float xr[NJ];
    {
        const v4f* xv = reinterpret_cast<const v4f*>(x + (size_t)b * NJ);
        #pragma unroll
        for (int c = 0; c < NJ / 4; ++c) {
            v4f v = __builtin_nontemporal_load(xv + c);
            xr[c * 4 + 0] = v.x; xr[c * 4 + 1] = v.y;
            xr[c * 4 + 2] = v.z; xr[c * 4 + 3] = v.w;
        }
    }

    // Weights: compile-time-constant indices off uniform kernel args ->
    // s_load_* into SGPRs; with L2 no longer swept by the streams these are
    // L2 hits (~200 cyc) instead of HBM misses (~900 cyc).
    float feats[NJ][FS];  // fully unrolled -> registers, ~3 joints live

    #pragma unroll
    for (int i = 0; i < NJ; ++i) {
        const int p = kParents[i];

        float inp[NF];
        inp[0] = xr[i];
        #pragma unroll
        for (int j = 0; j < FS; ++j) inp[1 + j] = (p < 0) ? 0.0f : feats[p][j];

        float h[NF];
        #pragma unroll
        for (int j = 0; j < NF; ++j) h[j] = b1[i * NF + j];
        #pragma unroll
        for (int k = 0; k < NF; ++k) {
            const float a = inp[k];
            #pragma unroll
            for (int j = 0; j < NF; ++j)
                h[j] = fmaf(a, W1[i * NF * NF + k * NF + j], h[j]);
        }
        #pragma unroll
        for (int j = 0; j < NF; ++j) h[j] = fmaxf(h[j], 0.0f);

        float f[FS];
        #pragma unroll
        for (int j = 0; j < FS; ++j) f[j] = b2[i * FS + j];
        #pragma unroll
        for (int k = 0; k < NF; ++k) {
            const float a = h[k];
            #pragma unroll
            for (int j = 0; j < FS; ++j)
                f[j] = fmaf(a, W2[i * NF * FS + k * FS + j], f[j]);
        }
        #pragma unroll
        for (int j = 0; j < FS; ++j) {
            f[j] = fmaxf(f[j], 0.0f);
            feats[i][j] = f[j];
        }

        // Stage joint-pair (12 floats = 3 float4) into wave-private LDS.
        if (i & 1) {
            const int pp = (i >> 1) & 3;  // pair index within current chunk
            float4* st = myStage + pp * 3;
            st[0] = make_float4(feats[i - 1][0], feats[i - 1][1],
                                feats[i - 1][2], feats[i - 1][3]);
            st[1] = make_float4(feats[i - 1][4], feats[i - 1][5], f[0], f[1]);
            st[2] = make_float4(f[2], f[3], f[4], f[5]);
        }

        // Every 8 joints, burst-flush the wave's chunk: 12 wave-stores, each
        // = 16 complete 64B lines (proven R3). Non-temporal: out is a
        // write-once stream -> don't let it claim L2 and evict the weights.
        if ((i & 7) == 7) {
            const int c = i >> 3;  // chunk 0..2
            #pragma unroll
            for (int j = 0; j < CUNITS; ++j) {
                const int G = j * 64 + lane;      // global float4 idx in chunk
                const int s = G / CUNITS;         // sample within wave (0..63)
                const int q = G - s * CUNITS;
                float4 v = sm[wid][s * PAD + q];
                __builtin_nontemporal_store(
                    *reinterpret_cast<v4f*>(&v),
                    outv + (size_t)wb * 36 + c * 12 + s * 36 + q);
            }
        }
    }
    (void)B;
}

extern "C" void kernel_launch(void* const* d_in, const int* in_sizes, int n_in,
                              void* d_out, int out_size, void* d_ws, size_t ws_size,
                              hipStream_t stream) {
    const float* x  = (const float*)d_in[0];
    const float* W1 = (const float*)d_in[1];
    const float* b1 = (const float*)d_in[2];
    const float* W2 = (const float*)d_in[3];
    const float* b2 = (const float*)d_in[4];
    float* out = (float*)d_out;
    const int B = in_sizes[0] / NJ;   // 524288, multiple of 256
    const int grid = B / THREADS;
    hipLaunchKernelGGL(se1d_kernel, dim3(grid), dim3(THREADS), 0, stream,
                       x, W1, b1, W2, b2, out, B);
}

// Round 9
// 92.826 us; speedup vs baseline: 1.9046x; 1.0374x over previous
//
#include <hip/hip_runtime.h>

#define NJ 24
#define NF 7
#define FS 6
#define THREADS 256
#define CUNITS 12   // float4 per thread per chunk (4 joint-pairs = 192 B)
#define PAD 13      // LDS stride in float4 units

typedef float v4f __attribute__((ext_vector_type(4)));

// parent of each joint; parents[i] < i, so sequential order is topological
__device__ constexpr int kParents[NJ] = {-1, 0, 0, 0, 1, 2, 3, 4, 5, 6, 7, 8,
                                          9, 9, 9, 12, 13, 14, 16, 17, 18, 19, 20, 21};

// Compute joint i; stage completed joint-pairs (3 x v4f) into wave-private LDS.
#define JOINT(i)                                                              \
    {                                                                         \
        const int p_ = kParents[i];                                           \
        float inp_[NF];                                                       \
        inp_[0] = xr[i];                                                      \
        _Pragma("unroll")                                                     \
        for (int j = 0; j < FS; ++j)                                          \
            inp_[1 + j] = (p_ < 0) ? 0.0f : feats[(p_ < 0) ? 0 : p_][j];      \
        float h_[NF];                                                         \
        _Pragma("unroll")                                                     \
        for (int j = 0; j < NF; ++j) h_[j] = b1[(i) * NF + j];                \
        _Pragma("unroll")                                                     \
        for (int k = 0; k < NF; ++k) {                                        \
            const float a_ = inp_[k];                                         \
            _Pragma("unroll")                                                 \
            for (int j = 0; j < NF; ++j)                                      \
                h_[j] = fmaf(a_, W1[(i) * NF * NF + k * NF + j], h_[j]);      \
        }                                                                     \
        _Pragma("unroll")                                                     \
        for (int j = 0; j < NF; ++j) h_[j] = fmaxf(h_[j], 0.0f);              \
        float f_[FS];                                                         \
        _Pragma("unroll")                                                     \
        for (int j = 0; j < FS; ++j) f_[j] = b2[(i) * FS + j];                \
        _Pragma("unroll")                                                     \
        for (int k = 0; k < NF; ++k) {                                        \
            const float a_ = h_[k];                                           \
            _Pragma("unroll")                                                 \
            for (int j = 0; j < FS; ++j)                                      \
                f_[j] = fmaf(a_, W2[(i) * NF * FS + k * FS + j], f_[j]);      \
        }                                                                     \
        _Pragma("unroll")                                                     \
        for (int j = 0; j < FS; ++j) {                                        \
            f_[j] = fmaxf(f_[j], 0.0f);                                       \
            feats[i][j] = f_[j];                                              \
        }                                                                     \
        if ((i) & 1) {                                                        \
            const int pp_ = ((i) >> 1) & 3;                                   \
            v4f* st_ = myStage + pp_ * 3;                                     \
            st_[0] = (v4f){feats[(i) - 1][0], feats[(i) - 1][1],              \
                           feats[(i) - 1][2], feats[(i) - 1][3]};             \
            st_[1] = (v4f){feats[(i) - 1][4], feats[(i) - 1][5],              \
                           f_[0], f_[1]};                                     \
            st_[2] = (v4f){f_[2], f_[3], f_[4], f_[5]};                       \
        }                                                                     \
    }

// Flush chunk C: 12 ds_read_b128 into a DEDICATED temp set FR (no reuse of a
// pending store's source until a full chunk later), then 12 fire-and-forget
// NT stores through the persistent read-only pointers ap[] (+imm offset).
// Each wave-store = 16 complete 64B lines (proven R3).
#define FLUSH(C, FR)                                                          \
    {                                                                         \
        _Pragma("unroll")                                                     \
        for (int j = 0; j < CUNITS; ++j) {                                    \
            const int G = j * 64 + lane;                                      \
            const int s = G / CUNITS;                                         \
            const int q = G - s * CUNITS;                                     \
            FR[j] = sm[wid][s * PAD + q];                                     \
        }                                                                     \
        _Pragma("unroll")                                                     \
        for (int j = 0; j < CUNITS; ++j)                                      \
            __builtin_nontemporal_store(FR[j], ap[j] + (C) * 12);             \
    }

// Keep a 12 x v4f set live to kernel end so the register allocator can never
// recycle a pending NT store's data regs into compute temps (which would make
// the waitcnt pass insert a store-drain vmcnt wait there).
#define KEEP12(A)                                                             \
    asm volatile("" :: "v"(A[0]), "v"(A[1]), "v"(A[2]), "v"(A[3]),            \
                 "v"(A[4]), "v"(A[5]), "v"(A[6]), "v"(A[7]),                  \
                 "v"(A[8]), "v"(A[9]), "v"(A[10]), "v"(A[11]));

// Requires B % 256 == 0 (bench: B = 524288).
__global__ __launch_bounds__(THREADS, 2) void se1d_kernel(
    const float* __restrict__ x,
    const float* __restrict__ W1,
    const float* __restrict__ b1,
    const float* __restrict__ W2,
    const float* __restrict__ b2,
    float* __restrict__ out, int B)
{
    // Wave-private staging: 64 lanes x 13 v4f = 13312 B/wave, 53 KB/block.
    // No barriers (wave-synchronous; per-wave DS pipe is in-order).
    __shared__ v4f sm[THREADS / 64][64 * PAD];

    const int t    = threadIdx.x;
    const int lane = t & 63;
    const int wid  = t >> 6;
    const int b    = blockIdx.x * THREADS + t;         // this thread's sample
    const int wb   = blockIdx.x * THREADS + wid * 64;  // wave's sample base

    v4f* const myStage = &sm[wid][lane * PAD];

    // Persistent store pointers: computed once, read-only afterwards (chunk
    // offset goes into the store's immediate: +0 / +192 / +384 bytes).
    v4f* ap[CUNITS];
    #pragma unroll
    for (int j = 0; j < CUNITS; ++j) {
        const int G = j * 64 + lane;
        const int s = G / CUNITS;
        const int q = G - s * CUNITS;
        ap[j] = reinterpret_cast<v4f*>(out) + (size_t)wb * 36 + s * 36 + q;
    }

    // ALL x loaded up-front (a mid-kernel load would vmcnt-wait on all older
    // NT stores: vmcnt is a single in-order counter). NT: read-once stream.
    float xr[NJ];
    {
        const v4f* xv = reinterpret_cast<const v4f*>(x + (size_t)b * NJ);
        #pragma unroll
        for (int c = 0; c < NJ / 4; ++c) {
            v4f v = __builtin_nontemporal_load(xv + c);
            xr[c * 4 + 0] = v.x; xr[c * 4 + 1] = v.y;
            xr[c * 4 + 2] = v.z; xr[c * 4 + 3] = v.w;
        }
    }

    float feats[NJ][FS];      // fully unrolled -> registers, ~3 joints live
    v4f fra[CUNITS], frb[CUNITS];  // ping-pong store-data sets

    // chunk 0
    JOINT(0) JOINT(1) JOINT(2) JOINT(3) JOINT(4) JOINT(5) JOINT(6) JOINT(7)
    FLUSH(0, fra);
    // chunk 1 (frb: fra's stores stay un-waited)
    JOINT(8) JOINT(9) JOINT(10) JOINT(11)
    JOINT(12) JOINT(13) JOINT(14) JOINT(15)
    FLUSH(1, frb);
    // chunk 2 (fra again: its chunk-0 stores had a full chunk+flush to drain)
    JOINT(16) JOINT(17) JOINT(18) JOINT(19)
    JOINT(20) JOINT(21) JOINT(22) JOINT(23)
    FLUSH(2, fra);

    KEEP12(fra);
    KEEP12(frb);
    (void)B;
}

extern "C" void kernel_launch(void* const* d_in, const int* in_sizes, int n_in,
                              void* d_out, int out_size, void* d_ws, size_t ws_size,
                              hipStream_t stream) {
    const float* x  = (const float*)d_in[0];
    const float* W1 = (const float*)d_in[1];
    const float* b1 = (const float*)d_in[2];
    const float* W2 = (const float*)d_in[3];
    const float* b2 = (const float*)d_in[4];
    float* out = (float*)d_out;
    const int B = in_sizes[0] / NJ;   // 524288, multiple of 256
    const int grid = B / THREADS;
    hipLaunchKernelGGL(se1d_kernel, dim3(grid), dim3(THREADS), 0, stream,
                       x, W1, b1, W2, b2, out, B);
}

// Round 10
// 92.552 us; speedup vs baseline: 1.9102x; 1.0030x over previous
//
#include <hip/hip_runtime.h>

#define NJ 24
#define NF 7
#define FS 6
#define THREADS 256
#define CUNITS 12   // float4 per thread per chunk (4 joint-pairs = 192 B)
#define PAD 13      // LDS stride in float4 units

typedef float v4f __attribute__((ext_vector_type(4)));

// parent of each joint; parents[i] < i, so sequential order is topological
__device__ constexpr int kParents[NJ] = {-1, 0, 0, 0, 1, 2, 3, 4, 5, 6, 7, 8,
                                          9, 9, 9, 12, 13, 14, 16, 17, 18, 19, 20, 21};

// Compute joint i; stage completed joint-pairs (3 x v4f) into wave-private LDS.
#define JOINT(i)                                                              \
    {                                                                         \
        const int p_ = kParents[i];                                           \
        float inp_[NF];                                                       \
        inp_[0] = xr[i];                                                      \
        _Pragma("unroll")                                                     \
        for (int j = 0; j < FS; ++j)                                          \
            inp_[1 + j] = (p_ < 0) ? 0.0f : feats[(p_ < 0) ? 0 : p_][j];      \
        float h_[NF];                                                         \
        _Pragma("unroll")                                                     \
        for (int j = 0; j < NF; ++j) h_[j] = b1[(i) * NF + j];                \
        _Pragma("unroll")                                                     \
        for (int k = 0; k < NF; ++k) {                                        \
            const float a_ = inp_[k];                                         \
            _Pragma("unroll")                                                 \
            for (int j = 0; j < NF; ++j)                                      \
                h_[j] = fmaf(a_, W1[(i) * NF * NF + k * NF + j], h_[j]);      \
        }                                                                     \
        _Pragma("unroll")                                                     \
        for (int j = 0; j < NF; ++j) h_[j] = fmaxf(h_[j], 0.0f);              \
        float f_[FS];                                                         \
        _Pragma("unroll")                                                     \
        for (int j = 0; j < FS; ++j) f_[j] = b2[(i) * FS + j];                \
        _Pragma("unroll")                                                     \
        for (int k = 0; k < NF; ++k) {                                        \
            const float a_ = h_[k];                                           \
            _Pragma("unroll")                                                 \
            for (int j = 0; j < FS; ++j)                                      \
                f_[j] = fmaf(a_, W2[(i) * NF * FS + k * FS + j], f_[j]);      \
        }                                                                     \
        _Pragma("unroll")                                                     \
        for (int j = 0; j < FS; ++j) {                                        \
            f_[j] = fmaxf(f_[j], 0.0f);                                       \
            feats[i][j] = f_[j];                                              \
        }                                                                     \
        if ((i) & 1) {                                                        \
            const int pp_ = ((i) >> 1) & 3;                                   \
            v4f* st_ = myStage + pp_ * 3;                                     \
            st_[0] = (v4f){feats[(i) - 1][0], feats[(i) - 1][1],              \
                           feats[(i) - 1][2], feats[(i) - 1][3]};             \
            st_[1] = (v4f){feats[(i) - 1][4], feats[(i) - 1][5],              \
                           f_[0], f_[1]};                                     \
            st_[2] = (v4f){f_[2], f_[3], f_[4], f_[5]};                       \
        }                                                                     \
    }

// Flush chunk C: 12 ds_read_b128 into the persistent set fr[] (overwritten
// only one full chunk after its previous stores issued -> ample drain slack),
// then 12 fire-and-forget NT stores: SGPR base (wave-uniform) + 32-bit VGPR
// byte offset + chunk imm (+0/+192/+384 B). Each store = 16 full 64B lines.
#define FLUSH(C)                                                              \
    {                                                                         \
        _Pragma("unroll")                                                     \
        for (int j = 0; j < CUNITS; ++j) {                                    \
            const int G = j * 64 + lane;                                      \
            const int s = G / CUNITS;                                         \
            const int q = G - s * CUNITS;                                     \
            fr[j] = sm[wid][s * PAD + q];                                     \
        }                                                                     \
        _Pragma("unroll")                                                     \
        for (int j = 0; j < CUNITS; ++j) {                                    \
            v4f* dst_ = reinterpret_cast<v4f*>(                               \
                reinterpret_cast<char*>(obase) + voff[j] + (C) * 192);        \
            __builtin_nontemporal_store(fr[j], dst_);                         \
        }                                                                     \
    }

// Pin the persistent store-data set to kernel end so the allocator can't
// recycle a pending store's source reg into a compute temp (would reinsert
// store-drain vmcnt waits in the middle of compute).
#define KEEP12(A)                                                             \
    asm volatile("" :: "v"(A[0]), "v"(A[1]), "v"(A[2]), "v"(A[3]),            \
                 "v"(A[4]), "v"(A[5]), "v"(A[6]), "v"(A[7]),                  \
                 "v"(A[8]), "v"(A[9]), "v"(A[10]), "v"(A[11]));

// Requires B % 256 == 0 (bench: B = 524288).
__global__ __launch_bounds__(THREADS, 3) void se1d_kernel(
    const float* __restrict__ x,
    const float* __restrict__ W1,
    const float* __restrict__ b1,
    const float* __restrict__ W2,
    const float* __restrict__ b2,
    float* __restrict__ out, int B)
{
    // Wave-private staging: 64 lanes x 13 v4f = 13312 B/wave, 53 KB/block
    // -> 3 blocks/CU (12 waves). No barriers (wave-synchronous; per-wave DS
    // pipe is in-order).
    __shared__ v4f sm[THREADS / 64][64 * PAD];

    const int t    = threadIdx.x;
    const int lane = t & 63;
    // readfirstlane makes wid (hence wb/obase) compiler-provably uniform ->
    // stores use SADDR form: SGPR base + 32b VGPR offset (saves 23 VGPRs vs
    // 12 pointer pairs).
    const int wid  = __builtin_amdgcn_readfirstlane(threadIdx.x >> 6);
    const int b    = blockIdx.x * THREADS + t;         // this thread's sample
    const int wb   = blockIdx.x * THREADS + wid * 64;  // wave base (uniform)

    v4f* const myStage = &sm[wid][lane * PAD];
    v4f* const obase = reinterpret_cast<v4f*>(out) + (size_t)wb * 36;

    // Per-lane store byte-offsets within the wave's 36 KB output region.
    int voff[CUNITS];
    #pragma unroll
    for (int j = 0; j < CUNITS; ++j) {
        const int G = j * 64 + lane;
        const int s = G / CUNITS;
        const int q = G - s * CUNITS;
        voff[j] = (s * 36 + q) * 16;   // bytes
    }

    // ALL x loaded up-front, non-temporal (read-once stream; mid-kernel loads
    // would vmcnt-wait on older NT stores).
    float xr[NJ];
    {
        const v4f* xv = reinterpret_cast<const v4f*>(x + (size_t)b * NJ);
        #pragma unroll
        for (int c = 0; c < NJ / 4; ++c) {
            v4f v = __builtin_nontemporal_load(xv + c);
            xr[c * 4 + 0] = v.x; xr[c * 4 + 1] = v.y;
            xr[c * 4 + 2] = v.z; xr[c * 4 + 3] = v.w;
        }
    }

    float feats[NJ][FS];  // fully unrolled -> registers, ~3 joints live
    v4f fr[CUNITS];       // persistent store-data set (48 VGPR, pinned)

    // chunk 0
    JOINT(0) JOINT(1) JOINT(2) JOINT(3) JOINT(4) JOINT(5) JOINT(6) JOINT(7)
    FLUSH(0);
    // chunk 1 (fr overwrite waits only on chunk-0's oldest store: ~5Kcyc old)
    JOINT(8) JOINT(9) JOINT(10) JOINT(11)
    JOINT(12) JOINT(13) JOINT(14) JOINT(15)
    FLUSH(1);
    // chunk 2
    JOINT(16) JOINT(17) JOINT(18) JOINT(19)
    JOINT(20) JOINT(21) JOINT(22) JOINT(23)
    FLUSH(2);

    KEEP12(fr);
    (void)B;
}

extern "C" void kernel_launch(void* const* d_in, const int* in_sizes, int n_in,
                              void* d_out, int out_size, void* d_ws, size_t ws_size,
                              hipStream_t stream) {
    const float* x  = (const float*)d_in[0];
    const float* W1 = (const float*)d_in[1];
    const float* b1 = (const float*)d_in[2];
    const float* W2 = (const float*)d_in[3];
    const float* b2 = (const float*)d_in[4];
    float* out = (float*)d_out;
    const int B = in_sizes[0] / NJ;   // 524288, multiple of 256
    const int grid = B / THREADS;
    hipLaunchKernelGGL(se1d_kernel, dim3(grid), dim3(THREADS), 0, stream,
                       x, W1, b1, W2, b2, out, B);
}